// Round 1
// baseline (8638.628 us; speedup 1.0000x reference)
//
#include <hip/hip_runtime.h>

#define N_NODES 100000
#define N_EDGES 1600000
#define HID 128
#define LAT 64
#define N_LAYERS 3
#define N_GRAPHS 1000
#define TM 64

// ---------------- copy: agg = h ----------------
__global__ __launch_bounds__(256) void copy_kernel(const float* __restrict__ in,
                                                   float* __restrict__ out, int n4) {
    int i = blockIdx.x * 256 + threadIdx.x;
    if (i < n4) ((float4*)out)[i] = ((const float4*)in)[i];
}

// ---------------- scatter: agg[dst] += h[src] ----------------
__global__ __launch_bounds__(256) void scatter_kernel(const float* __restrict__ h,
                                                      const int* __restrict__ ei,
                                                      float* __restrict__ agg) {
    long long tid = (long long)blockIdx.x * 256 + threadIdx.x;
    int e = (int)(tid >> 5);
    int q = (int)(tid & 31);
    if (e >= N_EDGES) return;
    int s = ei[e];
    int d = ei[N_EDGES + e];
    const float4 v = *(const float4*)(h + (size_t)s * HID + q * 4);
    float* p = agg + (size_t)d * HID + q * 4;
    atomicAdd(p + 0, v.x);
    atomicAdd(p + 1, v.y);
    atomicAdd(p + 2, v.z);
    atomicAdd(p + 3, v.w);
}

// ---------------- fused MLP: out = relu(relu(A@W1+b1)@W2+b2) ----------------
// Block: 256 threads. Tile: 64 rows x 128 cols. Microtile 8 rows x 4 cols/thread.
// LDS: sA[64][132] (A tile, then reused for H1), sW[32][132] (W K-chunk).
__global__ __launch_bounds__(256) void mlp_kernel(const float* __restrict__ A,
                                                  const float* __restrict__ W1,
                                                  const float* __restrict__ b1,
                                                  const float* __restrict__ W2,
                                                  const float* __restrict__ b2,
                                                  float* __restrict__ out) {
    __shared__ float sA[TM][132];
    __shared__ float sW[32][132];
    const int t = threadIdx.x;
    const int tr = t >> 5;   // 0..7  row group
    const int tc = t & 31;   // 0..31 col group
    const int row0 = blockIdx.x * TM;

    // load A tile (guarded)
    for (int idx = t; idx < TM * 32; idx += 256) {
        int r = idx >> 5, c4 = idx & 31;
        int grow = row0 + r;
        float4 v = make_float4(0.f, 0.f, 0.f, 0.f);
        if (grow < N_NODES) v = *(const float4*)(A + (size_t)grow * HID + c4 * 4);
        *(float4*)&sA[r][c4 * 4] = v;
    }

    float acc[8][4];
    const float* Wmats[2] = {W1, W2};
    const float* bvecs[2] = {b1, b2};

    for (int phase = 0; phase < 2; ++phase) {
        const float* W = Wmats[phase];
#pragma unroll
        for (int r = 0; r < 8; ++r)
#pragma unroll
            for (int c = 0; c < 4; ++c) acc[r][c] = 0.f;

        for (int kc = 0; kc < 4; ++kc) {
            __syncthreads();  // prior chunk reads done (and A-tile load done on first pass)
            for (int idx = t; idx < 32 * 32; idx += 256) {
                int r = idx >> 5, c4 = idx & 31;
                *(float4*)&sW[r][c4 * 4] =
                    *(const float4*)(W + (size_t)(kc * 32 + r) * HID + c4 * 4);
            }
            __syncthreads();
#pragma unroll
            for (int k0 = 0; k0 < 32; k0 += 4) {
                float4 a4[8];
#pragma unroll
                for (int r = 0; r < 8; ++r)
                    a4[r] = *(const float4*)&sA[tr * 8 + r][kc * 32 + k0];
#pragma unroll
                for (int kk = 0; kk < 4; ++kk) {
                    float4 w4 = *(const float4*)&sW[k0 + kk][tc * 4];
#pragma unroll
                    for (int r = 0; r < 8; ++r) {
                        float a = ((const float*)&a4[r])[kk];
                        acc[r][0] = fmaf(a, w4.x, acc[r][0]);
                        acc[r][1] = fmaf(a, w4.y, acc[r][1]);
                        acc[r][2] = fmaf(a, w4.z, acc[r][2]);
                        acc[r][3] = fmaf(a, w4.w, acc[r][3]);
                    }
                }
            }
        }
        __syncthreads();  // all sA reads finished before overwrite
        float4 bv = *(const float4*)(bvecs[phase] + tc * 4);
        if (phase == 0) {
#pragma unroll
            for (int r = 0; r < 8; ++r) {
                float4 hv;
                hv.x = fmaxf(acc[r][0] + bv.x, 0.f);
                hv.y = fmaxf(acc[r][1] + bv.y, 0.f);
                hv.z = fmaxf(acc[r][2] + bv.z, 0.f);
                hv.w = fmaxf(acc[r][3] + bv.w, 0.f);
                *(float4*)&sA[tr * 8 + r][tc * 4] = hv;
            }
            __syncthreads();
        } else {
#pragma unroll
            for (int r = 0; r < 8; ++r) {
                int grow = row0 + tr * 8 + r;
                if (grow < N_NODES) {
                    float4 hv;
                    hv.x = fmaxf(acc[r][0] + bv.x, 0.f);
                    hv.y = fmaxf(acc[r][1] + bv.y, 0.f);
                    hv.z = fmaxf(acc[r][2] + bv.z, 0.f);
                    hv.w = fmaxf(acc[r][3] + bv.w, 0.f);
                    *(float4*)(out + (size_t)grow * HID + tc * 4) = hv;
                }
            }
        }
    }
}

// ---------------- pool: g[batch[n]] += h[n] (batch sorted) ----------------
__global__ __launch_bounds__(128) void pool_kernel(const float* __restrict__ h,
                                                   const int* __restrict__ batch,
                                                   float* __restrict__ g) {
    const int CHUNK = 256;
    int c = threadIdx.x;  // channel
    int n0 = blockIdx.x * CHUNK;
    if (n0 >= N_NODES) return;
    int n1 = n0 + CHUNK;
    if (n1 > N_NODES) n1 = N_NODES;
    int cur = batch[n0];
    float acc = 0.f;
    for (int n = n0; n < n1; ++n) {
        int b = batch[n];
        if (b != cur) {
            atomicAdd(&g[(size_t)cur * HID + c], acc);
            acc = 0.f;
            cur = b;
        }
        acc += h[(size_t)n * HID + c];
    }
    atomicAdd(&g[(size_t)cur * HID + c], acc);
}

// ---------------- heads: mu = g@Wmu+bmu, logvar = g@Wlv+blv ----------------
__global__ __launch_bounds__(128) void head_kernel(const float* __restrict__ g,
                                                   const float* __restrict__ Wmu,
                                                   const float* __restrict__ bmu,
                                                   const float* __restrict__ Wlv,
                                                   const float* __restrict__ blv,
                                                   float* __restrict__ out) {
    __shared__ float sg[HID];
    int gi = blockIdx.x;
    sg[threadIdx.x] = g[(size_t)gi * HID + threadIdx.x];
    __syncthreads();
    int j = threadIdx.x & 63;
    bool is_lv = threadIdx.x >= 64;
    const float* W = is_lv ? Wlv : Wmu;
    float acc = is_lv ? blv[j] : bmu[j];
    for (int k = 0; k < HID; ++k) acc = fmaf(sg[k], W[k * LAT + j], acc);
    out[(is_lv ? (size_t)N_GRAPHS * LAT : 0) + (size_t)gi * LAT + j] = acc;
}

extern "C" void kernel_launch(void* const* d_in, const int* in_sizes, int n_in,
                              void* d_out, int out_size, void* d_ws, size_t ws_size,
                              hipStream_t stream) {
    const float* x     = (const float*)d_in[0];
    const int*   ei    = (const int*)d_in[1];   // [2, E] int32
    const int*   batch = (const int*)d_in[2];
    const float* W1    = (const float*)d_in[3]; // [3,128,128]
    const float* b1    = (const float*)d_in[4]; // [3,128]
    const float* W2    = (const float*)d_in[5];
    const float* b2    = (const float*)d_in[6];
    const float* Wmu   = (const float*)d_in[7]; // [128,64]
    const float* bmu   = (const float*)d_in[8];
    const float* Wlv   = (const float*)d_in[9];
    const float* blv   = (const float*)d_in[10];
    float* out = (float*)d_out;

    float* agg  = (float*)d_ws;                          // 51.2 MB
    float* hbuf = agg + (size_t)N_NODES * HID;           // 51.2 MB
    float* g    = hbuf + (size_t)N_NODES * HID;          // 512 KB

    const int n4 = N_NODES * HID / 4;
    const float* hcur = x;
    for (int i = 0; i < N_LAYERS; ++i) {
        copy_kernel<<<(n4 + 255) / 256, 256, 0, stream>>>(hcur, agg, n4);
        scatter_kernel<<<(N_EDGES * 32) / 256, 256, 0, stream>>>(hcur, ei, agg);
        mlp_kernel<<<(N_NODES + TM - 1) / TM, 256, 0, stream>>>(
            agg, W1 + (size_t)i * HID * HID, b1 + (size_t)i * HID,
            W2 + (size_t)i * HID * HID, b2 + (size_t)i * HID, hbuf);
        hcur = hbuf;
    }
    hipMemsetAsync(g, 0, (size_t)N_GRAPHS * HID * sizeof(float), stream);
    pool_kernel<<<(N_NODES + 255) / 256, 128, 0, stream>>>(hcur, batch, g);
    head_kernel<<<N_GRAPHS, 128, 0, stream>>>(g, Wmu, bmu, Wlv, blv, out);
}

// Round 2
// 1339.961 us; speedup vs baseline: 6.4469x; 6.4469x over previous
//
#include <hip/hip_runtime.h>

#define N_NODES 100000
#define N_EDGES 1600000
#define HID 128
#define LAT 64
#define N_LAYERS 3
#define N_GRAPHS 1000
#define TM 64

// ---------------- CSR build: count degrees by dst ----------------
__global__ __launch_bounds__(256) void count_kernel(const int* __restrict__ ei,
                                                    int* __restrict__ deg) {
    int e = blockIdx.x * 256 + threadIdx.x;
    if (e < N_EDGES) atomicAdd(&deg[ei[N_EDGES + e]], 1);
}

// ---------------- CSR build: exclusive scan (single block, 1024 thr) ----------------
__global__ __launch_bounds__(1024) void scan_kernel(const int* __restrict__ deg,
                                                    int* __restrict__ offs,
                                                    int* __restrict__ cursor) {
    __shared__ int sums[1024];
    const int PER = (N_NODES + 1023) / 1024;  // 98
    int t = threadIdx.x;
    int start = t * PER;
    int end = start + PER;
    if (end > N_NODES) end = N_NODES;
    int s = 0;
    for (int n = start; n < end; ++n) s += deg[n];
    sums[t] = s;
    __syncthreads();
    for (int d = 1; d < 1024; d <<= 1) {
        int v = (t >= d) ? sums[t - d] : 0;
        __syncthreads();
        sums[t] += v;
        __syncthreads();
    }
    int run = (t > 0) ? sums[t - 1] : 0;
    for (int n = start; n < end; ++n) {
        offs[n] = run;
        cursor[n] = run;
        run += deg[n];
    }
    if (t == 1023) offs[N_NODES] = sums[1023];
}

// ---------------- CSR build: place src ids into dst buckets ----------------
__global__ __launch_bounds__(256) void place_kernel(const int* __restrict__ ei,
                                                    int* __restrict__ cursor,
                                                    int* __restrict__ csr) {
    int e = blockIdx.x * 256 + threadIdx.x;
    if (e < N_EDGES) {
        int d = ei[N_EDGES + e];
        int pos = atomicAdd(&cursor[d], 1);
        csr[pos] = ei[e];
    }
}

// ---------------- gather: agg[n] = h[n] + sum_{s in N(n)} h[s] ----------------
// 32 threads per node (half-wave), thread q handles channels [4q, 4q+4).
__global__ __launch_bounds__(256) void gather_kernel(const float* __restrict__ h,
                                                     const int* __restrict__ offs,
                                                     const int* __restrict__ csr,
                                                     float* __restrict__ agg) {
    int t = threadIdx.x;
    int node = blockIdx.x * 8 + (t >> 5);
    int q = t & 31;
    if (node >= N_NODES) return;
    int off0 = offs[node], off1 = offs[node + 1];
    float4 acc = *(const float4*)(h + (size_t)node * HID + q * 4);
    int e = off0;
    for (; e + 4 <= off1; e += 4) {
        int s0 = csr[e], s1 = csr[e + 1], s2 = csr[e + 2], s3 = csr[e + 3];
        float4 v0 = *(const float4*)(h + (size_t)s0 * HID + q * 4);
        float4 v1 = *(const float4*)(h + (size_t)s1 * HID + q * 4);
        float4 v2 = *(const float4*)(h + (size_t)s2 * HID + q * 4);
        float4 v3 = *(const float4*)(h + (size_t)s3 * HID + q * 4);
        acc.x += v0.x + v1.x + v2.x + v3.x;
        acc.y += v0.y + v1.y + v2.y + v3.y;
        acc.z += v0.z + v1.z + v2.z + v3.z;
        acc.w += v0.w + v1.w + v2.w + v3.w;
    }
    for (; e < off1; ++e) {
        int s0 = csr[e];
        float4 v0 = *(const float4*)(h + (size_t)s0 * HID + q * 4);
        acc.x += v0.x; acc.y += v0.y; acc.z += v0.z; acc.w += v0.w;
    }
    *(float4*)(agg + (size_t)node * HID + q * 4) = acc;
}

// ---------------- fused MLP: out = relu(relu(A@W1+b1)@W2+b2) ----------------
__global__ __launch_bounds__(256) void mlp_kernel(const float* __restrict__ A,
                                                  const float* __restrict__ W1,
                                                  const float* __restrict__ b1,
                                                  const float* __restrict__ W2,
                                                  const float* __restrict__ b2,
                                                  float* __restrict__ out) {
    __shared__ float sA[TM][132];
    __shared__ float sW[32][132];
    const int t = threadIdx.x;
    const int tr = t >> 5;
    const int tc = t & 31;
    const int row0 = blockIdx.x * TM;

    for (int idx = t; idx < TM * 32; idx += 256) {
        int r = idx >> 5, c4 = idx & 31;
        int grow = row0 + r;
        float4 v = make_float4(0.f, 0.f, 0.f, 0.f);
        if (grow < N_NODES) v = *(const float4*)(A + (size_t)grow * HID + c4 * 4);
        *(float4*)&sA[r][c4 * 4] = v;
    }

    float acc[8][4];
    const float* Wmats[2] = {W1, W2};
    const float* bvecs[2] = {b1, b2};

    for (int phase = 0; phase < 2; ++phase) {
        const float* W = Wmats[phase];
#pragma unroll
        for (int r = 0; r < 8; ++r)
#pragma unroll
            for (int c = 0; c < 4; ++c) acc[r][c] = 0.f;

        for (int kc = 0; kc < 4; ++kc) {
            __syncthreads();
            for (int idx = t; idx < 32 * 32; idx += 256) {
                int r = idx >> 5, c4 = idx & 31;
                *(float4*)&sW[r][c4 * 4] =
                    *(const float4*)(W + (size_t)(kc * 32 + r) * HID + c4 * 4);
            }
            __syncthreads();
#pragma unroll
            for (int k0 = 0; k0 < 32; k0 += 4) {
                float4 a4[8];
#pragma unroll
                for (int r = 0; r < 8; ++r)
                    a4[r] = *(const float4*)&sA[tr * 8 + r][kc * 32 + k0];
#pragma unroll
                for (int kk = 0; kk < 4; ++kk) {
                    float4 w4 = *(const float4*)&sW[k0 + kk][tc * 4];
#pragma unroll
                    for (int r = 0; r < 8; ++r) {
                        float a = ((const float*)&a4[r])[kk];
                        acc[r][0] = fmaf(a, w4.x, acc[r][0]);
                        acc[r][1] = fmaf(a, w4.y, acc[r][1]);
                        acc[r][2] = fmaf(a, w4.z, acc[r][2]);
                        acc[r][3] = fmaf(a, w4.w, acc[r][3]);
                    }
                }
            }
        }
        __syncthreads();
        float4 bv = *(const float4*)(bvecs[phase] + tc * 4);
        if (phase == 0) {
#pragma unroll
            for (int r = 0; r < 8; ++r) {
                float4 hv;
                hv.x = fmaxf(acc[r][0] + bv.x, 0.f);
                hv.y = fmaxf(acc[r][1] + bv.y, 0.f);
                hv.z = fmaxf(acc[r][2] + bv.z, 0.f);
                hv.w = fmaxf(acc[r][3] + bv.w, 0.f);
                *(float4*)&sA[tr * 8 + r][tc * 4] = hv;
            }
            __syncthreads();
        } else {
#pragma unroll
            for (int r = 0; r < 8; ++r) {
                int grow = row0 + tr * 8 + r;
                if (grow < N_NODES) {
                    float4 hv;
                    hv.x = fmaxf(acc[r][0] + bv.x, 0.f);
                    hv.y = fmaxf(acc[r][1] + bv.y, 0.f);
                    hv.z = fmaxf(acc[r][2] + bv.z, 0.f);
                    hv.w = fmaxf(acc[r][3] + bv.w, 0.f);
                    *(float4*)(out + (size_t)grow * HID + tc * 4) = hv;
                }
            }
        }
    }
}

// ---------------- pool: g[batch[n]] += h[n] (batch sorted) ----------------
__global__ __launch_bounds__(128) void pool_kernel(const float* __restrict__ h,
                                                   const int* __restrict__ batch,
                                                   float* __restrict__ g) {
    const int CHUNK = 256;
    int c = threadIdx.x;
    int n0 = blockIdx.x * CHUNK;
    if (n0 >= N_NODES) return;
    int n1 = n0 + CHUNK;
    if (n1 > N_NODES) n1 = N_NODES;
    int cur = batch[n0];
    float acc = 0.f;
    for (int n = n0; n < n1; ++n) {
        int b = batch[n];
        if (b != cur) {
            atomicAdd(&g[(size_t)cur * HID + c], acc);
            acc = 0.f;
            cur = b;
        }
        acc += h[(size_t)n * HID + c];
    }
    atomicAdd(&g[(size_t)cur * HID + c], acc);
}

// ---------------- heads ----------------
__global__ __launch_bounds__(128) void head_kernel(const float* __restrict__ g,
                                                   const float* __restrict__ Wmu,
                                                   const float* __restrict__ bmu,
                                                   const float* __restrict__ Wlv,
                                                   const float* __restrict__ blv,
                                                   float* __restrict__ out) {
    __shared__ float sg[HID];
    int gi = blockIdx.x;
    sg[threadIdx.x] = g[(size_t)gi * HID + threadIdx.x];
    __syncthreads();
    int j = threadIdx.x & 63;
    bool is_lv = threadIdx.x >= 64;
    const float* W = is_lv ? Wlv : Wmu;
    float acc = is_lv ? blv[j] : bmu[j];
    for (int k = 0; k < HID; ++k) acc = fmaf(sg[k], W[k * LAT + j], acc);
    out[(is_lv ? (size_t)N_GRAPHS * LAT : 0) + (size_t)gi * LAT + j] = acc;
}

extern "C" void kernel_launch(void* const* d_in, const int* in_sizes, int n_in,
                              void* d_out, int out_size, void* d_ws, size_t ws_size,
                              hipStream_t stream) {
    const float* x     = (const float*)d_in[0];
    const int*   ei    = (const int*)d_in[1];
    const int*   batch = (const int*)d_in[2];
    const float* W1    = (const float*)d_in[3];
    const float* b1    = (const float*)d_in[4];
    const float* W2    = (const float*)d_in[5];
    const float* b2    = (const float*)d_in[6];
    const float* Wmu   = (const float*)d_in[7];
    const float* bmu   = (const float*)d_in[8];
    const float* Wlv   = (const float*)d_in[9];
    const float* blv   = (const float*)d_in[10];
    float* out = (float*)d_out;

    // workspace layout
    float* agg    = (float*)d_ws;                                  // 51.2 MB
    float* hbuf   = agg + (size_t)N_NODES * HID;                   // 51.2 MB
    float* g      = hbuf + (size_t)N_NODES * HID;                  // 512 KB
    int*   deg    = (int*)(g + (size_t)N_GRAPHS * HID);            // 400 KB
    int*   offs   = deg + N_NODES;                                 // 400 KB (+4)
    int*   cursor = offs + N_NODES + 1;                            // 400 KB
    int*   csr    = cursor + N_NODES;                              // 6.4 MB

    // ---- build CSR by dst (once per launch) ----
    hipMemsetAsync(deg, 0, (size_t)N_NODES * sizeof(int), stream);
    count_kernel<<<(N_EDGES + 255) / 256, 256, 0, stream>>>(ei, deg);
    scan_kernel<<<1, 1024, 0, stream>>>(deg, offs, cursor);
    place_kernel<<<(N_EDGES + 255) / 256, 256, 0, stream>>>(ei, cursor, csr);

    const float* hcur = x;
    for (int i = 0; i < N_LAYERS; ++i) {
        gather_kernel<<<(N_NODES + 7) / 8, 256, 0, stream>>>(hcur, offs, csr, agg);
        mlp_kernel<<<(N_NODES + TM - 1) / TM, 256, 0, stream>>>(
            agg, W1 + (size_t)i * HID * HID, b1 + (size_t)i * HID,
            W2 + (size_t)i * HID * HID, b2 + (size_t)i * HID, hbuf);
        hcur = hbuf;
    }
    hipMemsetAsync(g, 0, (size_t)N_GRAPHS * HID * sizeof(float), stream);
    pool_kernel<<<(N_NODES + 255) / 256, 128, 0, stream>>>(hcur, batch, g);
    head_kernel<<<N_GRAPHS, 128, 0, stream>>>(g, Wmu, bmu, Wlv, blv, out);
}

// Round 4
// 905.687 us; speedup vs baseline: 9.5382x; 1.4795x over previous
//
#include <hip/hip_runtime.h>

#define N_NODES 100000
#define N_EDGES 1600000
#define HID 128
#define LAT 64
#define N_LAYERS 3
#define N_GRAPHS 1000
#define NB_SCAN ((N_NODES + 255) / 256)  // 391
#define TM 64

__device__ __forceinline__ float bf2f(unsigned short h) {
    union { unsigned int u; float f; } c;
    c.u = ((unsigned int)h) << 16;
    return c.f;
}
__device__ __forceinline__ unsigned short f2bf(float f) {
    union { float f; unsigned int u; } c;
    c.f = f;
    unsigned int u = c.u;
    return (unsigned short)((u + 0x7fffu + ((u >> 16) & 1u)) >> 16);
}
__device__ __forceinline__ unsigned int pack2(float a, float b) {
    return (unsigned int)f2bf(a) | ((unsigned int)f2bf(b) << 16);
}

// ---------------- convert x fp32 -> bf16 ----------------
__global__ __launch_bounds__(256) void cvt_x_kernel(const float* __restrict__ x,
                                                    unsigned short* __restrict__ xb, int n4) {
    int i = blockIdx.x * 256 + threadIdx.x;
    if (i >= n4) return;
    float4 v = ((const float4*)x)[i];
    ((uint2*)xb)[i] = make_uint2(pack2(v.x, v.y), pack2(v.z, v.w));
}

// ---------------- W fp32 -> bf16 (same [k][n] layout, 6 matrices) ----------------
__global__ __launch_bounds__(256) void wcvt_kernel(const float* __restrict__ W1,
                                                   const float* __restrict__ W2,
                                                   unsigned short* __restrict__ Wb) {
    int m = blockIdx.x;  // 0..5 : layer*2 + phase
    const float* W = ((m & 1) ? W2 : W1) + (size_t)(m >> 1) * HID * HID;
    unsigned short* D = Wb + (size_t)m * HID * HID;
    for (int idx = threadIdx.x; idx < HID * HID / 4; idx += 256) {
        float4 v = ((const float4*)W)[idx];
        ((uint2*)D)[idx] = make_uint2(pack2(v.x, v.y), pack2(v.z, v.w));
    }
}

// ---------------- CSR build ----------------
__global__ __launch_bounds__(256) void count_kernel(const int* __restrict__ ei,
                                                    int* __restrict__ deg) {
    int e = blockIdx.x * 256 + threadIdx.x;
    if (e < N_EDGES) atomicAdd(&deg[ei[N_EDGES + e]], 1);
}

__global__ __launch_bounds__(256) void scanA_kernel(const int* __restrict__ deg,
                                                    int* __restrict__ bsum) {
    __shared__ int s[256];
    int t = threadIdx.x;
    int n = blockIdx.x * 256 + t;
    s[t] = (n < N_NODES) ? deg[n] : 0;
    __syncthreads();
    for (int d = 128; d > 0; d >>= 1) {
        if (t < d) s[t] += s[t + d];
        __syncthreads();
    }
    if (t == 0) bsum[blockIdx.x] = s[0];
}

__global__ __launch_bounds__(512) void scanB_kernel(const int* __restrict__ bsum,
                                                    int* __restrict__ boff) {
    __shared__ int s[512];
    int t = threadIdx.x;
    s[t] = (t < NB_SCAN) ? bsum[t] : 0;
    __syncthreads();
    for (int d = 1; d < 512; d <<= 1) {
        int v = (t >= d) ? s[t - d] : 0;
        __syncthreads();
        s[t] += v;
        __syncthreads();
    }
    if (t < NB_SCAN) boff[t] = (t == 0) ? 0 : s[t - 1];
}

__global__ __launch_bounds__(256) void scanC_kernel(const int* __restrict__ deg,
                                                    const int* __restrict__ boff,
                                                    int* __restrict__ offs,
                                                    int* __restrict__ cursor) {
    __shared__ int s[256];
    int t = threadIdx.x;
    int n = blockIdx.x * 256 + t;
    int v = (n < N_NODES) ? deg[n] : 0;
    s[t] = v;
    __syncthreads();
    for (int d = 1; d < 256; d <<= 1) {
        int u = (t >= d) ? s[t - d] : 0;
        __syncthreads();
        s[t] += u;
        __syncthreads();
    }
    if (n < N_NODES) {
        int bo = boff[blockIdx.x];
        int excl = bo + s[t] - v;
        offs[n] = excl;
        cursor[n] = excl;
        if (n == N_NODES - 1) offs[N_NODES] = bo + s[t];
    }
}

__global__ __launch_bounds__(256) void place_kernel(const int* __restrict__ ei,
                                                    int* __restrict__ cursor,
                                                    int* __restrict__ csr) {
    int e = blockIdx.x * 256 + threadIdx.x;
    if (e < N_EDGES) {
        int d = ei[N_EDGES + e];
        int pos = atomicAdd(&cursor[d], 1);
        csr[pos] = ei[e];
    }
}

// ---------------- gather (bf16): agg[n] = h[n] + sum_{s in N(n)} h[s] ----------------
__global__ __launch_bounds__(256) void gather_kernel(const unsigned short* __restrict__ h,
                                                     const int* __restrict__ offs,
                                                     const int* __restrict__ csr,
                                                     unsigned short* __restrict__ agg) {
    int t = threadIdx.x;
    int node = blockIdx.x * 16 + (t >> 4);
    int q = t & 15;
    if (node >= N_NODES) return;
    int off0 = offs[node], off1 = offs[node + 1];
    float acc[8];
    {
        uint4 w = *(const uint4*)(h + (size_t)node * HID + q * 8);
        acc[0] = bf2f((unsigned short)w.x); acc[1] = bf2f((unsigned short)(w.x >> 16));
        acc[2] = bf2f((unsigned short)w.y); acc[3] = bf2f((unsigned short)(w.y >> 16));
        acc[4] = bf2f((unsigned short)w.z); acc[5] = bf2f((unsigned short)(w.z >> 16));
        acc[6] = bf2f((unsigned short)w.w); acc[7] = bf2f((unsigned short)(w.w >> 16));
    }
    int e = off0;
    for (; e + 4 <= off1; e += 4) {
        int s0 = csr[e], s1 = csr[e + 1], s2 = csr[e + 2], s3 = csr[e + 3];
        uint4 w0 = *(const uint4*)(h + (size_t)s0 * HID + q * 8);
        uint4 w1 = *(const uint4*)(h + (size_t)s1 * HID + q * 8);
        uint4 w2 = *(const uint4*)(h + (size_t)s2 * HID + q * 8);
        uint4 w3 = *(const uint4*)(h + (size_t)s3 * HID + q * 8);
        acc[0] += bf2f((unsigned short)w0.x) + bf2f((unsigned short)w1.x)
                + bf2f((unsigned short)w2.x) + bf2f((unsigned short)w3.x);
        acc[1] += bf2f((unsigned short)(w0.x >> 16)) + bf2f((unsigned short)(w1.x >> 16))
                + bf2f((unsigned short)(w2.x >> 16)) + bf2f((unsigned short)(w3.x >> 16));
        acc[2] += bf2f((unsigned short)w0.y) + bf2f((unsigned short)w1.y)
                + bf2f((unsigned short)w2.y) + bf2f((unsigned short)w3.y);
        acc[3] += bf2f((unsigned short)(w0.y >> 16)) + bf2f((unsigned short)(w1.y >> 16))
                + bf2f((unsigned short)(w2.y >> 16)) + bf2f((unsigned short)(w3.y >> 16));
        acc[4] += bf2f((unsigned short)w0.z) + bf2f((unsigned short)w1.z)
                + bf2f((unsigned short)w2.z) + bf2f((unsigned short)w3.z);
        acc[5] += bf2f((unsigned short)(w0.z >> 16)) + bf2f((unsigned short)(w1.z >> 16))
                + bf2f((unsigned short)(w2.z >> 16)) + bf2f((unsigned short)(w3.z >> 16));
        acc[6] += bf2f((unsigned short)w0.w) + bf2f((unsigned short)w1.w)
                + bf2f((unsigned short)w2.w) + bf2f((unsigned short)w3.w);
        acc[7] += bf2f((unsigned short)(w0.w >> 16)) + bf2f((unsigned short)(w1.w >> 16))
                + bf2f((unsigned short)(w2.w >> 16)) + bf2f((unsigned short)(w3.w >> 16));
    }
    for (; e < off1; ++e) {
        int s0 = csr[e];
        uint4 w = *(const uint4*)(h + (size_t)s0 * HID + q * 8);
        acc[0] += bf2f((unsigned short)w.x); acc[1] += bf2f((unsigned short)(w.x >> 16));
        acc[2] += bf2f((unsigned short)w.y); acc[3] += bf2f((unsigned short)(w.y >> 16));
        acc[4] += bf2f((unsigned short)w.z); acc[5] += bf2f((unsigned short)(w.z >> 16));
        acc[6] += bf2f((unsigned short)w.w); acc[7] += bf2f((unsigned short)(w.w >> 16));
    }
    uint4 o;
    o.x = pack2(acc[0], acc[1]);
    o.y = pack2(acc[2], acc[3]);
    o.z = pack2(acc[4], acc[5]);
    o.w = pack2(acc[6], acc[7]);
    *(uint4*)(agg + (size_t)node * HID + q * 8) = o;
}

// ---------------- MLP (round-2-proven fp32 FMA core, bf16 I/O) ----------------
__global__ __launch_bounds__(256) void mlp_kernel(const unsigned short* __restrict__ A,
                                                  const unsigned short* __restrict__ W1b,
                                                  const float* __restrict__ b1,
                                                  const unsigned short* __restrict__ W2b,
                                                  const float* __restrict__ b2,
                                                  unsigned short* __restrict__ out) {
    __shared__ float sA[TM][132];
    __shared__ float sW[32][132];
    const int t = threadIdx.x;
    const int tr = t >> 5;
    const int tc = t & 31;
    const int row0 = blockIdx.x * TM;

    // stage A tile: bf16 -> fp32 (64 rows x 16 octets)
    for (int idx = t; idx < TM * 16; idx += 256) {
        int r = idx >> 4, c0 = (idx & 15) * 8;
        int grow = row0 + r;
        float4 lo = make_float4(0.f, 0.f, 0.f, 0.f), hi = lo;
        if (grow < N_NODES) {
            uint4 w = *(const uint4*)(A + (size_t)grow * HID + c0);
            lo.x = bf2f((unsigned short)w.x); lo.y = bf2f((unsigned short)(w.x >> 16));
            lo.z = bf2f((unsigned short)w.y); lo.w = bf2f((unsigned short)(w.y >> 16));
            hi.x = bf2f((unsigned short)w.z); hi.y = bf2f((unsigned short)(w.z >> 16));
            hi.z = bf2f((unsigned short)w.w); hi.w = bf2f((unsigned short)(w.w >> 16));
        }
        *(float4*)&sA[r][c0] = lo;
        *(float4*)&sA[r][c0 + 4] = hi;
    }

    float acc[8][4];
    const unsigned short* Wmats[2] = {W1b, W2b};
    const float* bvecs[2] = {b1, b2};

    for (int phase = 0; phase < 2; ++phase) {
        const unsigned short* W = Wmats[phase];
#pragma unroll
        for (int r = 0; r < 8; ++r)
#pragma unroll
            for (int c = 0; c < 4; ++c) acc[r][c] = 0.f;

        for (int kc = 0; kc < 4; ++kc) {
            __syncthreads();
            // stage W chunk: bf16 -> fp32 (32 rows x 16 octets)
            for (int idx = t; idx < 32 * 16; idx += 256) {
                int r = idx >> 4, c0 = (idx & 15) * 8;
                uint4 w = *(const uint4*)(W + (size_t)(kc * 32 + r) * HID + c0);
                float4 lo, hi;
                lo.x = bf2f((unsigned short)w.x); lo.y = bf2f((unsigned short)(w.x >> 16));
                lo.z = bf2f((unsigned short)w.y); lo.w = bf2f((unsigned short)(w.y >> 16));
                hi.x = bf2f((unsigned short)w.z); hi.y = bf2f((unsigned short)(w.z >> 16));
                hi.z = bf2f((unsigned short)w.w); hi.w = bf2f((unsigned short)(w.w >> 16));
                *(float4*)&sW[r][c0] = lo;
                *(float4*)&sW[r][c0 + 4] = hi;
            }
            __syncthreads();
#pragma unroll
            for (int k0 = 0; k0 < 32; k0 += 4) {
                float4 a4[8];
#pragma unroll
                for (int r = 0; r < 8; ++r)
                    a4[r] = *(const float4*)&sA[tr * 8 + r][kc * 32 + k0];
#pragma unroll
                for (int kk = 0; kk < 4; ++kk) {
                    float4 w4 = *(const float4*)&sW[k0 + kk][tc * 4];
#pragma unroll
                    for (int r = 0; r < 8; ++r) {
                        float a = ((const float*)&a4[r])[kk];
                        acc[r][0] = fmaf(a, w4.x, acc[r][0]);
                        acc[r][1] = fmaf(a, w4.y, acc[r][1]);
                        acc[r][2] = fmaf(a, w4.z, acc[r][2]);
                        acc[r][3] = fmaf(a, w4.w, acc[r][3]);
                    }
                }
            }
        }
        __syncthreads();
        float4 bv = *(const float4*)(bvecs[phase] + tc * 4);
        if (phase == 0) {
#pragma unroll
            for (int r = 0; r < 8; ++r) {
                float4 hv;
                hv.x = fmaxf(acc[r][0] + bv.x, 0.f);
                hv.y = fmaxf(acc[r][1] + bv.y, 0.f);
                hv.z = fmaxf(acc[r][2] + bv.z, 0.f);
                hv.w = fmaxf(acc[r][3] + bv.w, 0.f);
                *(float4*)&sA[tr * 8 + r][tc * 4] = hv;
            }
            __syncthreads();
        } else {
#pragma unroll
            for (int r = 0; r < 8; ++r) {
                int grow = row0 + tr * 8 + r;
                if (grow < N_NODES) {
                    float x0 = fmaxf(acc[r][0] + bv.x, 0.f);
                    float x1 = fmaxf(acc[r][1] + bv.y, 0.f);
                    float x2 = fmaxf(acc[r][2] + bv.z, 0.f);
                    float x3 = fmaxf(acc[r][3] + bv.w, 0.f);
                    *(uint2*)(out + (size_t)grow * HID + tc * 4) =
                        make_uint2(pack2(x0, x1), pack2(x2, x3));
                }
            }
        }
    }
}

// ---------------- pool: g[batch[n]] += h[n] (batch sorted, bf16 in, fp32 out) ----------------
__global__ __launch_bounds__(128) void pool_kernel(const unsigned short* __restrict__ h,
                                                   const int* __restrict__ batch,
                                                   float* __restrict__ g) {
    const int CHUNK = 256;
    int c = threadIdx.x;
    int n0 = blockIdx.x * CHUNK;
    if (n0 >= N_NODES) return;
    int n1 = n0 + CHUNK;
    if (n1 > N_NODES) n1 = N_NODES;
    int cur = batch[n0];
    float acc = 0.f;
    for (int n = n0; n < n1; ++n) {
        int b = batch[n];
        if (b != cur) {
            atomicAdd(&g[(size_t)cur * HID + c], acc);
            acc = 0.f;
            cur = b;
        }
        acc += bf2f(h[(size_t)n * HID + c]);
    }
    atomicAdd(&g[(size_t)cur * HID + c], acc);
}

// ---------------- heads ----------------
__global__ __launch_bounds__(128) void head_kernel(const float* __restrict__ g,
                                                   const float* __restrict__ Wmu,
                                                   const float* __restrict__ bmu,
                                                   const float* __restrict__ Wlv,
                                                   const float* __restrict__ blv,
                                                   float* __restrict__ out) {
    __shared__ float sg[HID];
    int gi = blockIdx.x;
    sg[threadIdx.x] = g[(size_t)gi * HID + threadIdx.x];
    __syncthreads();
    int j = threadIdx.x & 63;
    bool is_lv = threadIdx.x >= 64;
    const float* W = is_lv ? Wlv : Wmu;
    float acc = is_lv ? blv[j] : bmu[j];
    for (int k = 0; k < HID; ++k) acc = fmaf(sg[k], W[k * LAT + j], acc);
    out[(is_lv ? (size_t)N_GRAPHS * LAT : 0) + (size_t)gi * LAT + j] = acc;
}

extern "C" void kernel_launch(void* const* d_in, const int* in_sizes, int n_in,
                              void* d_out, int out_size, void* d_ws, size_t ws_size,
                              hipStream_t stream) {
    const float* x     = (const float*)d_in[0];
    const int*   ei    = (const int*)d_in[1];
    const int*   batch = (const int*)d_in[2];
    const float* W1    = (const float*)d_in[3];
    const float* b1    = (const float*)d_in[4];
    const float* W2    = (const float*)d_in[5];
    const float* b2    = (const float*)d_in[6];
    const float* Wmu   = (const float*)d_in[7];
    const float* bmu   = (const float*)d_in[8];
    const float* Wlv   = (const float*)d_in[9];
    const float* blv   = (const float*)d_in[10];
    float* out = (float*)d_out;

    float* g = (float*)d_ws;
    unsigned short* xb   = (unsigned short*)(g + (size_t)N_GRAPHS * HID);
    unsigned short* agg  = xb + (size_t)N_NODES * HID;
    unsigned short* hbuf = agg + (size_t)N_NODES * HID;
    unsigned short* Wb   = hbuf + (size_t)N_NODES * HID;
    int* deg    = (int*)(Wb + (size_t)6 * HID * HID);
    int* offs   = deg + N_NODES;
    int* cursor = offs + N_NODES + 1;
    int* bsum   = cursor + N_NODES;
    int* boff   = bsum + NB_SCAN;
    int* csr    = boff + NB_SCAN + 1;

    // ---- CSR build ----
    hipMemsetAsync(deg, 0, (size_t)N_NODES * sizeof(int), stream);
    count_kernel<<<(N_EDGES + 255) / 256, 256, 0, stream>>>(ei, deg);
    scanA_kernel<<<NB_SCAN, 256, 0, stream>>>(deg, bsum);
    scanB_kernel<<<1, 512, 0, stream>>>(bsum, boff);
    scanC_kernel<<<NB_SCAN, 256, 0, stream>>>(deg, boff, offs, cursor);
    place_kernel<<<(N_EDGES + 255) / 256, 256, 0, stream>>>(ei, cursor, csr);

    // ---- prep bf16 ----
    cvt_x_kernel<<<(N_NODES * HID / 4 + 255) / 256, 256, 0, stream>>>(x, xb,
                                                                      N_NODES * HID / 4);
    wcvt_kernel<<<6, 256, 0, stream>>>(W1, W2, Wb);

    const unsigned short* hcur = xb;
    for (int i = 0; i < N_LAYERS; ++i) {
        gather_kernel<<<(N_NODES + 15) / 16, 256, 0, stream>>>(hcur, offs, csr, agg);
        mlp_kernel<<<(N_NODES + TM - 1) / TM, 256, 0, stream>>>(
            agg, Wb + (size_t)(2 * i) * HID * HID, b1 + (size_t)i * HID,
            Wb + (size_t)(2 * i + 1) * HID * HID, b2 + (size_t)i * HID, hbuf);
        hcur = hbuf;
    }
    hipMemsetAsync(g, 0, (size_t)N_GRAPHS * HID * sizeof(float), stream);
    pool_kernel<<<(N_NODES + 255) / 256, 128, 0, stream>>>(hcur, batch, g);
    head_kernel<<<N_GRAPHS, 128, 0, stream>>>(g, Wmu, bmu, Wlv, blv, out);
}

// Round 5
// 644.779 us; speedup vs baseline: 13.3978x; 1.4046x over previous
//
#include <hip/hip_runtime.h>

#define N_NODES 100000
#define N_EDGES 1600000
#define HID 128
#define LAT 64
#define N_LAYERS 3
#define N_GRAPHS 1000
#define NB_SCAN ((N_NODES + 255) / 256)  // 391

typedef short bf16x8 __attribute__((ext_vector_type(8)));
typedef float f32x4 __attribute__((ext_vector_type(4)));

__device__ __forceinline__ float bf2f(unsigned short h) {
    union { unsigned int u; float f; } c;
    c.u = ((unsigned int)h) << 16;
    return c.f;
}
__device__ __forceinline__ unsigned short f2bf(float f) {
    union { float f; unsigned int u; } c;
    c.f = f;
    unsigned int u = c.u;
    return (unsigned short)((u + 0x7fffu + ((u >> 16) & 1u)) >> 16);
}
__device__ __forceinline__ unsigned int pack2(float a, float b) {
    return (unsigned int)f2bf(a) | ((unsigned int)f2bf(b) << 16);
}

// ---------------- convert x fp32 -> bf16 ----------------
__global__ __launch_bounds__(256) void cvt_x_kernel(const float* __restrict__ x,
                                                    unsigned short* __restrict__ xb, int n4) {
    int i = blockIdx.x * 256 + threadIdx.x;
    if (i >= n4) return;
    float4 v = ((const float4*)x)[i];
    ((uint2*)xb)[i] = make_uint2(pack2(v.x, v.y), pack2(v.z, v.w));
}

// ---------------- W [k][n] fp32 -> Wt [n][k] bf16, 6 matrices ----------------
__global__ __launch_bounds__(256) void wt_kernel(const float* __restrict__ W1,
                                                 const float* __restrict__ W2,
                                                 unsigned short* __restrict__ Wt) {
    int m = blockIdx.x;  // 0..5 : layer*2 + phase
    const float* W = ((m & 1) ? W2 : W1) + (size_t)(m >> 1) * HID * HID;
    unsigned short* D = Wt + (size_t)m * HID * HID;
    for (int idx = threadIdx.x; idx < HID * HID; idx += 256) {
        int n = idx >> 7, k = idx & 127;
        D[n * HID + k] = f2bf(W[k * HID + n]);
    }
}

// ---------------- CSR build ----------------
__global__ __launch_bounds__(256) void count_kernel(const int* __restrict__ ei,
                                                    int* __restrict__ deg) {
    int e = blockIdx.x * 256 + threadIdx.x;
    if (e < N_EDGES) atomicAdd(&deg[ei[N_EDGES + e]], 1);
}

__global__ __launch_bounds__(256) void scanA_kernel(const int* __restrict__ deg,
                                                    int* __restrict__ bsum) {
    __shared__ int s[256];
    int t = threadIdx.x;
    int n = blockIdx.x * 256 + t;
    s[t] = (n < N_NODES) ? deg[n] : 0;
    __syncthreads();
    for (int d = 128; d > 0; d >>= 1) {
        if (t < d) s[t] += s[t + d];
        __syncthreads();
    }
    if (t == 0) bsum[blockIdx.x] = s[0];
}

__global__ __launch_bounds__(512) void scanB_kernel(const int* __restrict__ bsum,
                                                    int* __restrict__ boff) {
    __shared__ int s[512];
    int t = threadIdx.x;
    s[t] = (t < NB_SCAN) ? bsum[t] : 0;
    __syncthreads();
    for (int d = 1; d < 512; d <<= 1) {
        int v = (t >= d) ? s[t - d] : 0;
        __syncthreads();
        s[t] += v;
        __syncthreads();
    }
    if (t < NB_SCAN) boff[t] = (t == 0) ? 0 : s[t - 1];
}

__global__ __launch_bounds__(256) void scanC_kernel(const int* __restrict__ deg,
                                                    const int* __restrict__ boff,
                                                    int* __restrict__ offs,
                                                    int* __restrict__ cursor) {
    __shared__ int s[256];
    int t = threadIdx.x;
    int n = blockIdx.x * 256 + t;
    int v = (n < N_NODES) ? deg[n] : 0;
    s[t] = v;
    __syncthreads();
    for (int d = 1; d < 256; d <<= 1) {
        int u = (t >= d) ? s[t - d] : 0;
        __syncthreads();
        s[t] += u;
        __syncthreads();
    }
    if (n < N_NODES) {
        int bo = boff[blockIdx.x];
        int excl = bo + s[t] - v;
        offs[n] = excl;
        cursor[n] = excl;
        if (n == N_NODES - 1) offs[N_NODES] = bo + s[t];
    }
}

__global__ __launch_bounds__(256) void place_kernel(const int* __restrict__ ei,
                                                    int* __restrict__ cursor,
                                                    int* __restrict__ csr) {
    int e = blockIdx.x * 256 + threadIdx.x;
    if (e < N_EDGES) {
        int d = ei[N_EDGES + e];
        int pos = atomicAdd(&cursor[d], 1);
        csr[pos] = ei[e];
    }
}

// ---------------- gather (bf16): agg[n] = h[n] + sum_{s in N(n)} h[s] ----------------
__global__ __launch_bounds__(256) void gather_kernel(const unsigned short* __restrict__ h,
                                                     const int* __restrict__ offs,
                                                     const int* __restrict__ csr,
                                                     unsigned short* __restrict__ agg) {
    int t = threadIdx.x;
    int node = blockIdx.x * 16 + (t >> 4);
    int q = t & 15;
    if (node >= N_NODES) return;
    int off0 = offs[node], off1 = offs[node + 1];
    float acc[8];
    {
        uint4 w = *(const uint4*)(h + (size_t)node * HID + q * 8);
        acc[0] = bf2f((unsigned short)w.x); acc[1] = bf2f((unsigned short)(w.x >> 16));
        acc[2] = bf2f((unsigned short)w.y); acc[3] = bf2f((unsigned short)(w.y >> 16));
        acc[4] = bf2f((unsigned short)w.z); acc[5] = bf2f((unsigned short)(w.z >> 16));
        acc[6] = bf2f((unsigned short)w.w); acc[7] = bf2f((unsigned short)(w.w >> 16));
    }
    int e = off0;
    for (; e + 4 <= off1; e += 4) {
        int s0 = csr[e], s1 = csr[e + 1], s2 = csr[e + 2], s3 = csr[e + 3];
        uint4 w0 = *(const uint4*)(h + (size_t)s0 * HID + q * 8);
        uint4 w1 = *(const uint4*)(h + (size_t)s1 * HID + q * 8);
        uint4 w2 = *(const uint4*)(h + (size_t)s2 * HID + q * 8);
        uint4 w3 = *(const uint4*)(h + (size_t)s3 * HID + q * 8);
        acc[0] += bf2f((unsigned short)w0.x) + bf2f((unsigned short)w1.x)
                + bf2f((unsigned short)w2.x) + bf2f((unsigned short)w3.x);
        acc[1] += bf2f((unsigned short)(w0.x >> 16)) + bf2f((unsigned short)(w1.x >> 16))
                + bf2f((unsigned short)(w2.x >> 16)) + bf2f((unsigned short)(w3.x >> 16));
        acc[2] += bf2f((unsigned short)w0.y) + bf2f((unsigned short)w1.y)
                + bf2f((unsigned short)w2.y) + bf2f((unsigned short)w3.y);
        acc[3] += bf2f((unsigned short)(w0.y >> 16)) + bf2f((unsigned short)(w1.y >> 16))
                + bf2f((unsigned short)(w2.y >> 16)) + bf2f((unsigned short)(w3.y >> 16));
        acc[4] += bf2f((unsigned short)w0.z) + bf2f((unsigned short)w1.z)
                + bf2f((unsigned short)w2.z) + bf2f((unsigned short)w3.z);
        acc[5] += bf2f((unsigned short)(w0.z >> 16)) + bf2f((unsigned short)(w1.z >> 16))
                + bf2f((unsigned short)(w2.z >> 16)) + bf2f((unsigned short)(w3.z >> 16));
        acc[6] += bf2f((unsigned short)w0.w) + bf2f((unsigned short)w1.w)
                + bf2f((unsigned short)w2.w) + bf2f((unsigned short)w3.w);
        acc[7] += bf2f((unsigned short)(w0.w >> 16)) + bf2f((unsigned short)(w1.w >> 16))
                + bf2f((unsigned short)(w2.w >> 16)) + bf2f((unsigned short)(w3.w >> 16));
    }
    for (; e < off1; ++e) {
        int s0 = csr[e];
        uint4 w = *(const uint4*)(h + (size_t)s0 * HID + q * 8);
        acc[0] += bf2f((unsigned short)w.x); acc[1] += bf2f((unsigned short)(w.x >> 16));
        acc[2] += bf2f((unsigned short)w.y); acc[3] += bf2f((unsigned short)(w.y >> 16));
        acc[4] += bf2f((unsigned short)w.z); acc[5] += bf2f((unsigned short)(w.z >> 16));
        acc[6] += bf2f((unsigned short)w.w); acc[7] += bf2f((unsigned short)(w.w >> 16));
    }
    uint4 o;
    o.x = pack2(acc[0], acc[1]);
    o.y = pack2(acc[2], acc[3]);
    o.z = pack2(acc[4], acc[5]);
    o.w = pack2(acc[6], acc[7]);
    *(uint4*)(agg + (size_t)node * HID + q * 8) = o;
}

// ---------------- MFMA MLP: out = relu(relu(A@W1+b1)@W2+b2), bf16 io ----------------
// Block 256 = 4 waves. Tile 64 rows x 128 cols. Wave w owns rows [w*16, w*16+16).
// a_frag: A[m=lane&15][k=quad*8+j]; b_frag: B[k=quad*8+j][n] from Wt[n][k].
// C/D: n=lane&15, m=quad*4+reg. (m89/m91-verified mappings)
__global__ __launch_bounds__(256) void mlp_kernel(const unsigned short* __restrict__ A,
                                                  const unsigned short* __restrict__ W1t,
                                                  const float* __restrict__ b1,
                                                  const unsigned short* __restrict__ W2t,
                                                  const float* __restrict__ b2,
                                                  unsigned short* __restrict__ out) {
    __shared__ unsigned short sA[64][136];  // row stride 272B = 17*16B
    __shared__ unsigned short sW[128][40];  // row stride 80B = 5*16B
    __shared__ float sb[128];
    const int t = threadIdx.x;
    const int w = t >> 6;
    const int l = t & 63;
    const int lm = l & 15;
    const int quad = l >> 4;
    const int row0 = blockIdx.x * 64;

    // A tile: 64 rows x 16 octets (FULL 128 columns — round-3 bug was idx<512/c&7)
    for (int idx = t; idx < 1024; idx += 256) {
        int r = idx >> 4, c = idx & 15;
        int grow = row0 + r;
        uint4 v = make_uint4(0u, 0u, 0u, 0u);
        if (grow < N_NODES) v = *(const uint4*)(A + (size_t)grow * HID + c * 8);
        *(uint4*)&sA[r][c * 8] = v;
    }

    const unsigned short* Wt[2] = {W1t, W2t};
    const float* bias[2] = {b1, b2};

    for (int p = 0; p < 2; ++p) {
        if (t < 128) sb[t] = bias[p][t];
        f32x4 acc[8];
#pragma unroll
        for (int nt = 0; nt < 8; ++nt) acc[nt] = (f32x4){0.f, 0.f, 0.f, 0.f};

        for (int kc = 0; kc < 4; ++kc) {
            __syncthreads();
            // W chunk: sW[n][kk] = Wt[n][kc*32+kk]  (128 n-rows x 4 octets = 512)
            for (int idx = t; idx < 512; idx += 256) {
                int n = idx >> 2, kq = idx & 3;
                *(uint4*)&sW[n][kq * 8] =
                    *(const uint4*)(Wt[p] + (size_t)n * HID + kc * 32 + kq * 8);
            }
            __syncthreads();
            bf16x8 a = *(const bf16x8*)&sA[w * 16 + lm][kc * 32 + quad * 8];
#pragma unroll
            for (int nt = 0; nt < 8; ++nt) {
                bf16x8 b = *(const bf16x8*)&sW[nt * 16 + lm][quad * 8];
                acc[nt] = __builtin_amdgcn_mfma_f32_16x16x32_bf16(a, b, acc[nt], 0, 0, 0);
            }
        }
        __syncthreads();  // all sA/sW reads done before overwrite
#pragma unroll
        for (int nt = 0; nt < 8; ++nt) {
            float bv = sb[nt * 16 + lm];
#pragma unroll
            for (int r = 0; r < 4; ++r) {
                int m = w * 16 + quad * 4 + r;
                float val = fmaxf(acc[nt][r] + bv, 0.f);
                sA[m][nt * 16 + lm] = f2bf(val);
            }
        }
        __syncthreads();
    }
    // store FULL tile (round-3 bug: only half was stored)
    for (int idx = t; idx < 1024; idx += 256) {
        int r = idx >> 4, c = idx & 15;
        int grow = row0 + r;
        if (grow < N_NODES)
            *(uint4*)(out + (size_t)grow * HID + c * 8) = *(const uint4*)&sA[r][c * 8];
    }
}

// ---------------- pool: g[batch[n]] += h[n] (batch sorted, bf16 in, fp32 out) ----------------
__global__ __launch_bounds__(128) void pool_kernel(const unsigned short* __restrict__ h,
                                                   const int* __restrict__ batch,
                                                   float* __restrict__ g) {
    const int CHUNK = 256;
    int c = threadIdx.x;
    int n0 = blockIdx.x * CHUNK;
    if (n0 >= N_NODES) return;
    int n1 = n0 + CHUNK;
    if (n1 > N_NODES) n1 = N_NODES;
    int cur = batch[n0];
    float acc = 0.f;
    for (int n = n0; n < n1; ++n) {
        int b = batch[n];
        if (b != cur) {
            atomicAdd(&g[(size_t)cur * HID + c], acc);
            acc = 0.f;
            cur = b;
        }
        acc += bf2f(h[(size_t)n * HID + c]);
    }
    atomicAdd(&g[(size_t)cur * HID + c], acc);
}

// ---------------- heads ----------------
__global__ __launch_bounds__(128) void head_kernel(const float* __restrict__ g,
                                                   const float* __restrict__ Wmu,
                                                   const float* __restrict__ bmu,
                                                   const float* __restrict__ Wlv,
                                                   const float* __restrict__ blv,
                                                   float* __restrict__ out) {
    __shared__ float sg[HID];
    int gi = blockIdx.x;
    sg[threadIdx.x] = g[(size_t)gi * HID + threadIdx.x];
    __syncthreads();
    int j = threadIdx.x & 63;
    bool is_lv = threadIdx.x >= 64;
    const float* W = is_lv ? Wlv : Wmu;
    float acc = is_lv ? blv[j] : bmu[j];
    for (int k = 0; k < HID; ++k) acc = fmaf(sg[k], W[k * LAT + j], acc);
    out[(is_lv ? (size_t)N_GRAPHS * LAT : 0) + (size_t)gi * LAT + j] = acc;
}

extern "C" void kernel_launch(void* const* d_in, const int* in_sizes, int n_in,
                              void* d_out, int out_size, void* d_ws, size_t ws_size,
                              hipStream_t stream) {
    const float* x     = (const float*)d_in[0];
    const int*   ei    = (const int*)d_in[1];
    const int*   batch = (const int*)d_in[2];
    const float* W1    = (const float*)d_in[3];
    const float* b1    = (const float*)d_in[4];
    const float* W2    = (const float*)d_in[5];
    const float* b2    = (const float*)d_in[6];
    const float* Wmu   = (const float*)d_in[7];
    const float* bmu   = (const float*)d_in[8];
    const float* Wlv   = (const float*)d_in[9];
    const float* blv   = (const float*)d_in[10];
    float* out = (float*)d_out;

    float* g = (float*)d_ws;
    unsigned short* xb   = (unsigned short*)(g + (size_t)N_GRAPHS * HID);
    unsigned short* agg  = xb + (size_t)N_NODES * HID;
    unsigned short* hbuf = agg + (size_t)N_NODES * HID;
    unsigned short* Wt   = hbuf + (size_t)N_NODES * HID;
    int* deg    = (int*)(Wt + (size_t)6 * HID * HID);
    int* offs   = deg + N_NODES;
    int* cursor = offs + N_NODES + 1;
    int* bsum   = cursor + N_NODES;
    int* boff   = bsum + NB_SCAN;
    int* csr    = boff + NB_SCAN + 1;

    // ---- CSR build ----
    hipMemsetAsync(deg, 0, (size_t)N_NODES * sizeof(int), stream);
    count_kernel<<<(N_EDGES + 255) / 256, 256, 0, stream>>>(ei, deg);
    scanA_kernel<<<NB_SCAN, 256, 0, stream>>>(deg, bsum);
    scanB_kernel<<<1, 512, 0, stream>>>(bsum, boff);
    scanC_kernel<<<NB_SCAN, 256, 0, stream>>>(deg, boff, offs, cursor);
    place_kernel<<<(N_EDGES + 255) / 256, 256, 0, stream>>>(ei, cursor, csr);

    // ---- prep bf16 ----
    cvt_x_kernel<<<(N_NODES * HID / 4 + 255) / 256, 256, 0, stream>>>(x, xb,
                                                                      N_NODES * HID / 4);
    wt_kernel<<<6, 256, 0, stream>>>(W1, W2, Wt);

    const unsigned short* hcur = xb;
    for (int i = 0; i < N_LAYERS; ++i) {
        gather_kernel<<<(N_NODES + 15) / 16, 256, 0, stream>>>(hcur, offs, csr, agg);
        mlp_kernel<<<(N_NODES + 63) / 64, 256, 0, stream>>>(
            agg, Wt + (size_t)(2 * i) * HID * HID, b1 + (size_t)i * HID,
            Wt + (size_t)(2 * i + 1) * HID * HID, b2 + (size_t)i * HID, hbuf);
        hcur = hbuf;
    }
    hipMemsetAsync(g, 0, (size_t)N_GRAPHS * HID * sizeof(float), stream);
    pool_kernel<<<(N_NODES + 255) / 256, 128, 0, stream>>>(hcur, batch, g);
    head_kernel<<<N_GRAPHS, 128, 0, stream>>>(g, Wmu, bmu, Wlv, blv, out);
}